// Round 11
// baseline (99.650 us; speedup 1.0000x reference)
//
#include <hip/hip_runtime.h>

// maTransformerBlock fused kernel for MI355X (gfx950) — R10
//
// Shuffle algebra: with output batch b' = k*1024 + j (k in [0,32), j in [0,1024)):
//   source batch = 32 j + n', chunk = k.
// => block j handles source batches 32j..32j+31 and output batches {k*1024 + j}.
//
// R10 = R9 (barrier-free, per-wave private staging, free-running waves) with
// staging vectorized to float4 (G13: 16 B/lane): VMEM instrs 13->4 and
// ds_write 13->4 (b32->b128) per phase. Each wave-row (103 f) = 26 float4
// covering LDS slots 0..103 (slot 103 loaded, never consumed by conv).
// Global float4 addrs are 4B-aligned only (103 odd) — legal on gfx950
// (unaligned-access-mode). The two phases whose last float4 would read 4 B
// past the input buffer (prot c=20, dna c=3) use the scalar path => no OOB.
// LDS 34.8 KB -> 4 blocks/CU; grid 1024 = 4 x 256 CUs fully resident.

constexpr int NB      = 32;
constexpr int THREADS = 256;
constexpr int NBLOCKS = 1024;

__global__ __launch_bounds__(THREADS, 4)
void fused_matx(const float* __restrict__ dna,
                const float* __restrict__ prot,
                const float* __restrict__ wdna,
                const float* __restrict__ wprot,
                const float* __restrict__ wlin,
                const float* __restrict__ blin,
                float* __restrict__ out)
{
    __shared__ __align__(16) float s_stage[4 * 832];   // 4 waves x 8 rows x 104f, 13312B
    __shared__ float4 s_d4[32 * 40];                   // [ob][slot=cs+xb], 20480B
    __shared__ float2 s_red[128];                      // [wave][ob] partials, 1024B

    const int tid  = threadIdx.x;
    const int j    = blockIdx.x;
    const int w    = tid >> 6;       // wave 0..3 (owns rows 8w..8w+7)
    const int lane = tid & 63;
    const int cs   = tid >> 3;       // conv row (source batch slot) 0..31
    const int xb   = tid & 7;        // conv x-block 0..7 (12 outputs)

    // ---- vec staging geometry: 8 rows x 26 float4 = 208 items, 4 iters ----
    int gP4[4], gD4[4], lO4[4];
#pragma unroll
    for (int k = 0; k < 4; ++k) {
        int i = lane + 64 * k; if (i > 207) i = 207;   // dup lanes: same addr+data
        int r  = i / 26;                               // wave-local row 0..7
        int pf = (i - r * 26) * 4;                     // float pos 0,4,...,100
        gP4[k] = r * 2163 + pf;                        // prot global float offset
        gD4[k] = r * 412  + pf;                        // dna  global float offset
        lO4[k] = w * 832 + r * 104 + pf;               // LDS slot (16B aligned)
    }

    const float* dbase = dna  + (size_t)(j * NB + 8 * w) * 412;
    const float* pbase = prot + (size_t)(j * NB + 8 * w) * 2163;

    union Buf { float s[16]; float4 v[4]; };
    Buf A, B;

    auto ldP4 = [&](int c, Buf& b) {
        const float* g = pbase + c * 103;
#pragma unroll
        for (int k = 0; k < 4; ++k)
            b.v[k] = *reinterpret_cast<const float4*>(g + gP4[k]);
    };
    auto ldD4 = [&](int c, Buf& b) {
        const float* g = dbase + c * 103;
#pragma unroll
        for (int k = 0; k < 4; ++k)
            b.v[k] = *reinterpret_cast<const float4*>(g + gD4[k]);
    };
    auto st4 = [&](Buf& b) {
#pragma unroll
        for (int k = 0; k < 4; ++k)
            *reinterpret_cast<float4*>(&s_stage[lO4[k]]) = b.v[k];
    };
    // scalar path for the two buffer-end phases (prot c=20, dna c=3): no OOB
    auto ldS = [&](const float* base, int rs, int c, Buf& b) {
#pragma unroll
        for (int k = 0; k < 13; ++k) {
            int i = lane + 64 * k; if (i > 823) i = 823;
            int r = i / 103;
            int p = i - r * 103;
            b.s[k] = base[c * 103 + r * rs + p];
        }
    };
    auto stS = [&](Buf& b) {
#pragma unroll
        for (int k = 0; k < 13; ++k) {
            int i = lane + 64 * k; if (i > 823) i = 823;
            int r = i / 103;
            int p = i - r * 103;
            s_stage[w * 832 + r * 104 + p] = b.s[k];
        }
    };
    auto conv8 = [&](const float* __restrict__ wsrc, int c, float (&acc)[12]) {
        float wv[8];
#pragma unroll
        for (int f = 0; f < 8; ++f) wv[f] = wsrc[c * 8 + f];   // uniform -> SGPR
        float in[20];
        const float4* sp = reinterpret_cast<const float4*>(
            &s_stage[w * 832 + (cs & 7) * 104 + 12 * xb]);     // 16B aligned
#pragma unroll
        for (int u = 0; u < 5; ++u) {                          // 5 ds_read_b128
            float4 v = sp[u];
            in[4*u+0] = v.x; in[4*u+1] = v.y; in[4*u+2] = v.z; in[4*u+3] = v.w;
        }
#pragma unroll
        for (int f = 0; f < 8; ++f)
#pragma unroll
            for (int o = 0; o < 12; ++o)
                acc[o] = fmaf(in[o + f], wv[f], acc[o]);
    };

    float dacc[12], pacc[12];
#pragma unroll
    for (int o = 0; o < 12; ++o) { dacc[o] = 0.f; pacc[o] = 0.f; }

    // ======== 25 barrier-free phases: ld(t+1); st(t) [counted vmcnt]; conv(t)
    ldP4(0, A);
    ldP4(1, B); st4(A); conv8(wprot, 0, pacc);
    for (int c = 2; c < 20; c += 2) {
        ldP4(c,     A); st4(B); conv8(wprot, c - 1, pacc);
        ldP4(c + 1, B); st4(A); conv8(wprot, c,     pacc);
    }
    ldS(pbase, 2163, 20, A); st4(B); conv8(wprot, 19, pacc);   // P19 staged (vec)
    ldD4(0, B);              stS(A); conv8(wprot, 20, pacc);   // P20 staged (scalar)
    ldD4(1, A);              st4(B); conv8(wdna, 0, dacc);
    ldD4(2, B);              st4(A); conv8(wdna, 1, dacc);
    ldS(dbase, 412, 3, A);   st4(B); conv8(wdna, 2, dacc);
                             stS(A); conv8(wdna, 3, dacc);     // D3 (scalar)

    // ======== publish relu'd dna conv to the d-plane ========
    // layout [ob][slot = cs+xb], stride 40 float4 (conflict-free, R5-verified)
#pragma unroll
    for (int u = 0; u < 4; ++u) {
        float4 v;
        v.x = fmaxf(dacc[3*u+0], 0.f);
        v.y = fmaxf(dacc[3*u+1], 0.f);
        v.z = fmaxf(dacc[3*u+2], 0.f);
        v.w = 0.f;
        s_d4[(4 * xb + u) * 40 + cs + xb] = v;
    }
    __syncthreads();                       // barrier #1 (of 2)

    // ================= attention (32x32, d=3) + linear =================
    // thread (cs,xb): qr = cs (own pacc), ob = 4xb+it. d-reads: base + imm only.
    const float4* dp = s_d4 + 161 * xb;    // (4xb)*40 + xb
    float wl0[3], wl1[3];
#pragma unroll
    for (int t = 0; t < 3; ++t) {
        wl0[t] = wlin[3 * cs + t];
        wl1[t] = wlin[96 + 3 * cs + t];
    }
    const float escale = 0.5773502691896258f;  // 1/sqrt(3); logits bounded << 88

#pragma unroll
    for (int it = 0; it < 4; ++it) {
        const float q0 = fmaxf(pacc[3*it+0], 0.f);
        const float q1 = fmaxf(pacc[3*it+1], 0.f);
        const float q2 = fmaxf(pacc[3*it+2], 0.f);

        float sum = 0.f, v0 = 0.f, v1 = 0.f, v2 = 0.f;
#pragma unroll
        for (int r = 0; r < 32; ++r) {     // conflict-free broadcast b128 reads
            float4 dv = dp[40 * it + r];   // = s_d4[ob*40 + (r+xb)] = row r of ob
            float l = fmaf(q0, dv.x, fmaf(q1, dv.y, q2 * dv.z));
            float e = __expf(l * escale);
            sum += e;
            v0 = fmaf(e, dv.x, v0);
            v1 = fmaf(e, dv.y, v1);
            v2 = fmaf(e, dv.z, v2);
        }
        const float inv = 1.f / sum;
        float o0 = (wl0[0] * v0 + wl0[1] * v1 + wl0[2] * v2) * inv;
        float o1 = (wl1[0] * v0 + wl1[1] * v1 + wl1[2] * v2) * inv;
        // reduce over the 8 cs rows in this wave (lane bits 3..5)
        o0 += __shfl_xor(o0, 8);  o1 += __shfl_xor(o1, 8);
        o0 += __shfl_xor(o0, 16); o1 += __shfl_xor(o1, 16);
        o0 += __shfl_xor(o0, 32); o1 += __shfl_xor(o1, 32);
        if ((tid & 56) == 0)               // one lane per (wave, xb)
            s_red[w * 32 + 4 * xb + it] = make_float2(o0, o1);
    }
    __syncthreads();                       // barrier #2 (of 2)

    if (tid < 32) {                        // combine 4 wave-partials + bias
        float2 a = s_red[tid], b = s_red[32 + tid], c = s_red[64 + tid], d = s_red[96 + tid];
        float2 r;
        r.x = a.x + b.x + c.x + d.x + blin[0];
        r.y = a.y + b.y + c.y + d.y + blin[1];
        *reinterpret_cast<float2*>(&out[(size_t)((tid << 10) + j) * 2]) = r;
    }
}

extern "C" void kernel_launch(void* const* d_in, const int* in_sizes, int n_in,
                              void* d_out, int out_size, void* d_ws, size_t ws_size,
                              hipStream_t stream) {
    const float* dna   = (const float*)d_in[0];
    const float* prot  = (const float*)d_in[1];
    const float* wdna  = (const float*)d_in[2];
    const float* wprot = (const float*)d_in[3];
    const float* wlin  = (const float*)d_in[4];
    const float* blin  = (const float*)d_in[5];
    float* out = (float*)d_out;

    fused_matx<<<NBLOCKS, THREADS, 0, stream>>>(dna, prot, wdna, wprot, wlin, blin, out);
}

// Round 12
// 64.179 us; speedup vs baseline: 1.5527x; 1.5527x over previous
//
#include <hip/hip_runtime.h>

// maTransformerBlock fused kernel for MI355X (gfx950) — R11
//
// Shuffle algebra: with output batch b' = k*1024 + j (k in [0,32), j in [0,1024)):
//   source batch = 32 j + n', chunk = k.
// => block j handles source batches 32j..32j+31 and output batches {k*1024 + j}.
//
// R11 = R9 (barrier-free per-wave private staging, dword loads — R10 proved
// float4 is alignment-blocked by the odd row strides) with the schedule
// REORDERED: dna conv first -> publish d-plane -> the ONE barrier (waves have
// barely diverged; nearly free) -> 21 barrier-free prot phases -> attention
// with NO barrier. Waves/blocks drift apart during prot conv, so the
// LDS-pipe-bound attention tail of early waves overlaps the HBM-bound conv
// of late ones instead of stacking into a dead ~10us tail behind a re-sync.
// LDS 34.8 KB -> 4 blocks/CU; grid 1024 = 4 x 256 CUs fully resident.

constexpr int NB      = 32;
constexpr int THREADS = 256;
constexpr int NBLOCKS = 1024;

__global__ __launch_bounds__(THREADS, 4)
void fused_matx(const float* __restrict__ dna,
                const float* __restrict__ prot,
                const float* __restrict__ wdna,
                const float* __restrict__ wprot,
                const float* __restrict__ wlin,
                const float* __restrict__ blin,
                float* __restrict__ out)
{
    __shared__ __align__(16) float s_stage[4 * 832];   // 4 waves x 8 rows x 104f, 13312B
    __shared__ float4 s_d4[32 * 40];                   // [ob][slot=cs+xb], 20480B
    __shared__ float2 s_red[128];                      // [wave][ob] partials, 1024B

    const int tid  = threadIdx.x;
    const int j    = blockIdx.x;
    const int w    = tid >> 6;       // wave 0..3 (owns rows 8w..8w+7)
    const int lane = tid & 63;
    const int cs   = tid >> 3;       // conv row (source batch slot) 0..31
    const int xb   = tid & 7;        // conv x-block 0..7 (12 outputs)

    // ---- per-lane staging geometry (computed once) ----
    // wave slab per phase = 8 rows x 103 floats = 824; i = lane + 64k, k=0..12
    int gP[13], gD[13], lOf[13];
#pragma unroll
    for (int k = 0; k < 13; ++k) {
        int i = lane + 64 * k;
        if (i > 823) i = 823;            // tail lanes duplicate elt 823 (benign)
        int r = i / 103;                 // wave-local row 0..7 (magic-mul, once)
        int p = i - r * 103;
        gP[k]  = r * 2163 + p;           // prot global float offset (channel 0)
        gD[k]  = r * 412  + p;           // dna  global float offset (channel 0)
        lOf[k] = w * 832 + r * 104 + p;  // padded LDS slot
    }

    const float* dbase = dna  + (size_t)(j * NB + 8 * w) * 412;
    const float* pbase = prot + (size_t)(j * NB + 8 * w) * 2163;

    float pfA[13], pfB[13];

    auto ldP = [&](int c, float (&pf)[13]) {
        const float* b = pbase + c * 103;
#pragma unroll
        for (int k = 0; k < 13; ++k) pf[k] = b[gP[k]];
    };
    auto ldD = [&](int c, float (&pf)[13]) {
        const float* b = dbase + c * 103;
#pragma unroll
        for (int k = 0; k < 13; ++k) pf[k] = b[gD[k]];
    };
    auto st = [&](float (&pf)[13]) {
#pragma unroll
        for (int k = 0; k < 13; ++k) s_stage[lOf[k]] = pf[k];
    };
    auto conv8 = [&](const float* __restrict__ wsrc, int c, float (&acc)[12]) {
        float wv[8];
#pragma unroll
        for (int f = 0; f < 8; ++f) wv[f] = wsrc[c * 8 + f];   // uniform -> SGPR
        float in[20];
        const float4* sp = reinterpret_cast<const float4*>(
            &s_stage[w * 832 + (cs & 7) * 104 + 12 * xb]);     // 16B aligned
#pragma unroll
        for (int u = 0; u < 5; ++u) {                          // 5 ds_read_b128
            float4 v = sp[u];
            in[4*u+0] = v.x; in[4*u+1] = v.y; in[4*u+2] = v.z; in[4*u+3] = v.w;
        }
#pragma unroll
        for (int f = 0; f < 8; ++f)
#pragma unroll
            for (int o = 0; o < 12; ++o)
                acc[o] = fmaf(in[o + f], wv[f], acc[o]);
    };

    float dacc[12], pacc[12];
#pragma unroll
    for (int o = 0; o < 12; ++o) { dacc[o] = 0.f; pacc[o] = 0.f; }

    // ======== dna conv first: 4 barrier-free phases ========
    ldD(0, pfA);
    ldD(1, pfB); st(pfA); conv8(wdna, 0, dacc);
    ldD(2, pfA); st(pfB); conv8(wdna, 1, dacc);
    ldD(3, pfB); st(pfA); conv8(wdna, 2, dacc);
    ldP(0, pfA); st(pfB); conv8(wdna, 3, dacc);

    // publish relu'd dna conv to the d-plane: [ob][slot=cs+xb], stride 40
#pragma unroll
    for (int u = 0; u < 4; ++u) {
        float4 v;
        v.x = fmaxf(dacc[3*u+0], 0.f);
        v.y = fmaxf(dacc[3*u+1], 0.f);
        v.z = fmaxf(dacc[3*u+2], 0.f);
        v.w = 0.f;
        s_d4[(4 * xb + u) * 40 + cs + xb] = v;
    }
    __syncthreads();   // the ONLY pre-attention barrier — waves barely diverged yet

    // ======== prot conv: 21 barrier-free phases (waves drift apart) ========
    ldP(1, pfB); st(pfA); conv8(wprot, 0, pacc);
    for (int c = 2; c < 20; c += 2) {
        ldP(c,     pfA); st(pfB); conv8(wprot, c - 1, pacc);
        ldP(c + 1, pfB); st(pfA); conv8(wprot, c,     pacc);
    }
    ldP(20, pfA); st(pfB); conv8(wprot, 19, pacc);
                  st(pfA); conv8(wprot, 20, pacc);

    // ================= attention (32x32, d=3) + linear — NO barrier =========
    // d-plane was published before the early barrier; ~50us of margin since.
    // thread (cs,xb): qr = cs (own pacc), ob = 4xb+it. d-reads: base + imm only.
    const float4* dp = s_d4 + 161 * xb;    // (4xb)*40 + xb
    float wl0[3], wl1[3];
#pragma unroll
    for (int t = 0; t < 3; ++t) {
        wl0[t] = wlin[3 * cs + t];
        wl1[t] = wlin[96 + 3 * cs + t];
    }
    const float escale = 0.5773502691896258f;  // 1/sqrt(3); logits bounded << 88

#pragma unroll
    for (int it = 0; it < 4; ++it) {
        const float q0 = fmaxf(pacc[3*it+0], 0.f);
        const float q1 = fmaxf(pacc[3*it+1], 0.f);
        const float q2 = fmaxf(pacc[3*it+2], 0.f);

        float sum = 0.f, v0 = 0.f, v1 = 0.f, v2 = 0.f;
#pragma unroll
        for (int r = 0; r < 32; ++r) {     // conflict-free broadcast b128 reads
            float4 dv = dp[40 * it + r];   // = s_d4[ob*40 + (r+xb)] = row r of ob
            float l = fmaf(q0, dv.x, fmaf(q1, dv.y, q2 * dv.z));
            float e = __expf(l * escale);
            sum += e;
            v0 = fmaf(e, dv.x, v0);
            v1 = fmaf(e, dv.y, v1);
            v2 = fmaf(e, dv.z, v2);
        }
        const float inv = 1.f / sum;
        float o0 = (wl0[0] * v0 + wl0[1] * v1 + wl0[2] * v2) * inv;
        float o1 = (wl1[0] * v0 + wl1[1] * v1 + wl1[2] * v2) * inv;
        // reduce over the 8 cs rows in this wave (lane bits 3..5)
        o0 += __shfl_xor(o0, 8);  o1 += __shfl_xor(o1, 8);
        o0 += __shfl_xor(o0, 16); o1 += __shfl_xor(o1, 16);
        o0 += __shfl_xor(o0, 32); o1 += __shfl_xor(o1, 32);
        if ((tid & 56) == 0)               // one lane per (wave, xb)
            s_red[w * 32 + 4 * xb + it] = make_float2(o0, o1);
    }
    __syncthreads();                       // final reduction barrier

    if (tid < 32) {                        // combine 4 wave-partials + bias
        float2 a = s_red[tid], b = s_red[32 + tid], c = s_red[64 + tid], d = s_red[96 + tid];
        float2 r;
        r.x = a.x + b.x + c.x + d.x + blin[0];
        r.y = a.y + b.y + c.y + d.y + blin[1];
        *reinterpret_cast<float2*>(&out[(size_t)((tid << 10) + j) * 2]) = r;
    }
}

extern "C" void kernel_launch(void* const* d_in, const int* in_sizes, int n_in,
                              void* d_out, int out_size, void* d_ws, size_t ws_size,
                              hipStream_t stream) {
    const float* dna   = (const float*)d_in[0];
    const float* prot  = (const float*)d_in[1];
    const float* wdna  = (const float*)d_in[2];
    const float* wprot = (const float*)d_in[3];
    const float* wlin  = (const float*)d_in[4];
    const float* blin  = (const float*)d_in[5];
    float* out = (float*)d_out;

    fused_matx<<<NBLOCKS, THREADS, 0, stream>>>(dna, prot, wdna, wprot, wlin, blin, out);
}